// Round 4
// baseline (905.092 us; speedup 1.0000x reference)
//
#include <hip/hip_runtime.h>
#include <hip/hip_bf16.h>

typedef __bf16 bf16_t;
typedef __bf16 bf16x4 __attribute__((ext_vector_type(4)));
typedef __bf16 bf16x8 __attribute__((ext_vector_type(8)));
typedef float f32x4 __attribute__((ext_vector_type(4)));

#define B_   2
#define L_   4096
#define DIM_ 1024
#define M_   (B_ * L_)          // 8192 total rows
#define MT_  (L_ / 128)         // 32 m-tiles per batch
#define NTASK_ ((MT_ * (MT_ + 1)) / 2)   // 528 lower-tri tiles per batch

// ---- async global->LDS, 16B per lane (wave-uniform LDS base + lane*16) ----
__device__ __forceinline__ void ld_g2l_16(const bf16_t* g, bf16_t* l) {
  __builtin_amdgcn_global_load_lds(
      (__attribute__((address_space(1))) void*)g,
      (__attribute__((address_space(3))) void*)l, 16, 0, 0);
}

// ---- fused fp32->bf16 convert; W rows permuted so rope pairs (t,t+512)
// become adjacent output columns (2t, 2t+1). Same permutation for Wq,Wk
// leaves q.k dot products invariant. ----
__global__ void cvt_all(const float* __restrict__ hs, const float* __restrict__ wq,
                        const float* __restrict__ wk, bf16_t* __restrict__ hs_b,
                        bf16_t* __restrict__ wq_b, bf16_t* __restrict__ wk_b) {
  const int N_HS = M_ * DIM_ / 4, N_W = DIM_ * DIM_ / 4;
  int i = blockIdx.x * blockDim.x + threadIdx.x;
  const float* s; bf16_t* d; int idx, dst;
  if (i < N_HS) { s = hs; d = hs_b; idx = i; dst = i; }
  else {
    int iw = i - N_HS;
    if (iw < N_W) { s = wq; d = wq_b; } else { s = wk; d = wk_b; iw -= N_W; }
    idx = iw;
    int r = iw >> 8, c4 = iw & 255;                 // 256 float4 per row
    int pr = (r < 512) ? 2 * r : 2 * (r - 512) + 1; // pairing permutation
    dst = pr * 256 + c4;
  }
  float4 v = ((const float4*)s)[idx];
  bf16x4 o = { (bf16_t)v.x, (bf16_t)v.y, (bf16_t)v.z, (bf16_t)v.w };
  ((bf16x4*)d)[dst] = o;
}

// ---- pipelined 128x128 bt-GEMM K-loop, K=1024, BK=32 ----
// wave grid 2x2: wave owns 64m x 64n. A-frags loaded DIRECT from global
// (wave rows private-ish; l16=row, quad=k-chunk -> contiguous 16B).
// B staged in LDS, double-buffered 2x8KB, XOR-swizzled (0 conflicts, R3).
// ONE __syncthreads per kk: its vmcnt drain waits on loads issued a full
// compute-phase earlier (true 1-deep prefetch).
__device__ __forceinline__ void k_loop(const bf16_t* __restrict__ A,
                                       const bf16_t* __restrict__ B,
                                       bf16_t* Bs, f32x4 (&acc)[4][4]) {
  const int tid = threadIdx.x, wave = tid >> 6, lane = tid & 63;
  const int quad = lane >> 4, l16 = lane & 15;
  const int srow = lane >> 2;                              // 0..15 in segment
  const int scol = ((lane & 3) ^ ((lane >> 3) & 3)) * 8;   // swizzled chunk
  const int rsw  = ((l16 >> 1) & 3) * 8;                   // read-side swizzle
  const int wm = (wave >> 1) * 64, wnseg = (wave & 1) * 4;

  auto stage = [&](int buf, int kk) {
#pragma unroll
    for (int c = 0; c < 2; ++c) {
      int seg = c * 4 + wave;                    // 8 segs of 16 rows x 32 cols
      int row = seg * 16 + srow;
      ld_g2l_16(B + (size_t)row * DIM_ + kk + scol, Bs + buf * 4096 + seg * 512);
    }
  };
  auto loadA = [&](bf16x8 (&af)[4], int kk) {
#pragma unroll
    for (int i = 0; i < 4; ++i)
      af[i] = *(const bf16x8*)(A + (size_t)(wm + i * 16 + l16) * DIM_ + kk + quad * 8);
  };

  bf16x8 af[4], afn[4];
  stage(0, 0);
  loadA(af, 0);
#pragma unroll 2
  for (int kk = 0; kk < DIM_; kk += 32) {
    int buf = (kk >> 5) & 1;
    int kkn = (kk + 32 < DIM_) ? kk + 32 : 0;    // last-iter clamp (harmless refetch)
    __syncthreads();                             // drains prefetch; WAR-protects buf^1
    stage(buf ^ 1, kkn);                         // prefetch next B tile
    loadA(afn, kkn);                             // prefetch next A frags
    bf16x8 bfr[4];
#pragma unroll
    for (int j = 0; j < 4; ++j)
      bfr[j] = *(const bf16x8*)(Bs + buf * 4096 + (wnseg + j) * 512 + l16 * 32 +
                                ((quad * 8) ^ rsw));
#pragma unroll
    for (int i = 0; i < 4; ++i)
#pragma unroll
      for (int j = 0; j < 4; ++j)
        acc[i][j] = __builtin_amdgcn_mfma_f32_16x16x32_bf16(af[i], bfr[j],
                                                            acc[i][j], 0, 0, 0);
#pragma unroll
    for (int i = 0; i < 4; ++i) af[i] = afn[i];  // SSA rename, no copies
  }
}

// ---- projection GEMM + fused RoPE epilogue: C = rope(A @ W'^T) ----
// Permuted cols: even c -> orig t=c>>1 (first half), odd c -> orig t+512.
// Partner element is the adjacent lane (shfl_xor 1).
__global__ __launch_bounds__(256, 3)
void proj_gemm(const bf16_t* __restrict__ A, const bf16_t* __restrict__ Wqb,
               const bf16_t* __restrict__ Wkb, bf16_t* __restrict__ Cq,
               bf16_t* __restrict__ Ck) {
  const bf16_t* Bm = (blockIdx.z == 0) ? Wqb : Wkb;
  bf16_t* Cm = (blockIdx.z == 0) ? Cq : Ck;
  __shared__ __attribute__((aligned(16))) bf16_t Bs[2 * 4096];
  const int tid = threadIdx.x;
  const int wave = tid >> 6, lane = tid & 63;
  const int quad = lane >> 4, l16 = lane & 15;
  const int wm = (wave >> 1) * 64, wn = (wave & 1) * 64;
  const int m0 = blockIdx.y * 128, n0 = blockIdx.x * 128;

  f32x4 acc[4][4] = {};
  k_loop(A + (size_t)m0 * DIM_, Bm + (size_t)n0 * DIM_, Bs, acc);

#pragma unroll
  for (int i = 0; i < 4; ++i)
#pragma unroll
    for (int j = 0; j < 4; ++j)
#pragma unroll
      for (int r = 0; r < 4; ++r) {
        int m = m0 + wm + i * 16 + quad * 4 + r;   // C/D: row=quad*4+reg
        int c = n0 + wn + j * 16 + l16;            //      col=lane&15
        float val = (float)(bf16_t)acc[i][j][r];   // ref: q cast to bf16 pre-rope
        float par = __shfl_xor(val, 1);
        int t = c >> 1;
        int pos = m & (L_ - 1);
        float ang = (float)pos * exp2f((float)t * (-5.0f / 512.0f));
        float cb = (float)(bf16_t)cosf(ang), sb = (float)(bf16_t)sinf(ang);
        float ov = (c & 1) ? (val * cb + par * sb) : (val * cb - par * sb);
        Cm[(size_t)m * DIM_ + c] = (bf16_t)ov;
      }
}

// ---- causal exp-rowsum: o[b,m] = sum_{n<=m} exp(q_m . k_n / 32) ----
__global__ __launch_bounds__(256, 3)
void attn_rowsum(const bf16_t* __restrict__ Q, const bf16_t* __restrict__ Kc,
                 float* __restrict__ o) {
  int t = blockIdx.x;
  int b = t / NTASK_;
  t -= b * NTASK_;
  int mi = (int)((sqrtf(8.0f * (float)t + 1.0f) - 1.0f) * 0.5f);
  while ((mi + 1) * (mi + 2) / 2 <= t) ++mi;
  while (mi * (mi + 1) / 2 > t) --mi;
  int nt = t - mi * (mi + 1) / 2;

  __shared__ __attribute__((aligned(16))) bf16_t Bs[2 * 4096];
  const int tid = threadIdx.x;
  const int wave = tid >> 6, lane = tid & 63;
  const int quad = lane >> 4, l16 = lane & 15;
  const int wm = (wave >> 1) * 64, wn = (wave & 1) * 64;

  const bf16_t* A  = Q  + (size_t)b * L_ * DIM_ + (size_t)mi * 128 * DIM_;
  const bf16_t* Bp = Kc + (size_t)b * L_ * DIM_ + (size_t)nt * 128 * DIM_;

  f32x4 acc[4][4] = {};
  k_loop(A, Bp, Bs, acc);

  const bool masked = (nt == mi);   // tile touches the diagonal
#pragma unroll
  for (int i = 0; i < 4; ++i) {
#pragma unroll
    for (int r = 0; r < 4; ++r) {
      int grow = mi * 128 + wm + i * 16 + quad * 4 + r;   // row in batch
      float sum = 0.0f;
#pragma unroll
      for (int j = 0; j < 4; ++j) {
        int gcol = nt * 128 + wn + j * 16 + l16;
        float e = __expf(acc[i][j][r] * 0.03125f);        // /sqrt(1024)
        if (!masked || gcol <= grow) sum += e;
      }
      sum += __shfl_xor(sum, 1);
      sum += __shfl_xor(sum, 2);
      sum += __shfl_xor(sum, 4);
      sum += __shfl_xor(sum, 8);
      if (l16 == 0)
        atomicAdd(&o[b * L_ + grow], sum);
    }
  }
}

// ---- tiny MLP epilogue ----
__global__ __launch_bounds__(256)
void mlp_out_kernel(const float* __restrict__ o, const float* __restrict__ fc1_w,
                    const float* __restrict__ fc1_b, const float* __restrict__ fc2_w,
                    const float* __restrict__ fc2_b, float* __restrict__ out) {
  const int R = 16;
  int row0 = blockIdx.x * R;
  int tid = threadIdx.x;
  __shared__ float h[R][16];
  {
    int rl = tid >> 4, i = tid & 15;
    float s = o[row0 + rl];
    h[rl][i] = fmaxf(fc1_w[i] * s + fc1_b[i], 0.0f);
  }
  __syncthreads();
  int d = tid * 4;
  float w[4][16];
#pragma unroll
  for (int c = 0; c < 4; ++c)
#pragma unroll
    for (int i = 0; i < 16; ++i) w[c][i] = fc2_w[(d + c) * 16 + i];
  float4 bb = *(const float4*)(fc2_b + d);
  for (int rl = 0; rl < R; ++rl) {
    float4 v = bb;
#pragma unroll
    for (int i = 0; i < 16; ++i) {
      float hv = h[rl][i];
      v.x += w[0][i] * hv; v.y += w[1][i] * hv;
      v.z += w[2][i] * hv; v.w += w[3][i] * hv;
    }
    *(float4*)(out + (size_t)(row0 + rl) * DIM_ + d) = v;
  }
}

extern "C" void kernel_launch(void* const* d_in, const int* in_sizes, int n_in,
                              void* d_out, int out_size, void* d_ws, size_t ws_size,
                              hipStream_t stream) {
  const float* hs    = (const float*)d_in[0];
  const float* Wq    = (const float*)d_in[1];
  const float* Wk    = (const float*)d_in[2];
  const float* fc1_w = (const float*)d_in[3];
  const float* fc1_b = (const float*)d_in[4];
  const float* fc2_w = (const float*)d_in[5];
  const float* fc2_b = (const float*)d_in[6];
  float* out = (float*)d_out;

  char* ws = (char*)d_ws;
  bf16_t* hs_bf = (bf16_t*)ws; ws += (size_t)M_ * DIM_ * 2;
  bf16_t* wq_bf = (bf16_t*)ws; ws += (size_t)DIM_ * DIM_ * 2;
  bf16_t* wk_bf = (bf16_t*)ws; ws += (size_t)DIM_ * DIM_ * 2;
  bf16_t* q_bf  = (bf16_t*)ws; ws += (size_t)M_ * DIM_ * 2;
  bf16_t* k_bf  = (bf16_t*)ws; ws += (size_t)M_ * DIM_ * 2;
  float*  o     = (float*)ws;  // M_ floats

  const int n4 = (M_ * DIM_ + 2 * DIM_ * DIM_) / 4;
  cvt_all<<<n4 / 256, 256, 0, stream>>>(hs, Wq, Wk, hs_bf, wq_bf, wk_bf);

  hipMemsetAsync(o, 0, M_ * sizeof(float), stream);

  dim3 gg(DIM_ / 128, M_ / 128, 2);
  proj_gemm<<<gg, 256, 0, stream>>>(hs_bf, wq_bf, wk_bf, q_bf, k_bf);

  attn_rowsum<<<B_ * NTASK_, 256, 0, stream>>>(q_bf, k_bf, o);

  mlp_out_kernel<<<M_ / 16, 256, 0, stream>>>(o, fc1_w, fc1_b, fc2_w, fc2_b, out);
}

// Round 5
// 812.296 us; speedup vs baseline: 1.1142x; 1.1142x over previous
//
#include <hip/hip_runtime.h>
#include <hip/hip_bf16.h>

typedef __bf16 bf16_t;
typedef __bf16 bf16x4 __attribute__((ext_vector_type(4)));
typedef __bf16 bf16x8 __attribute__((ext_vector_type(8)));
typedef float f32x4 __attribute__((ext_vector_type(4)));

#define B_   2
#define L_   4096
#define DIM_ 1024
#define M_   (B_ * L_)          // 8192 total rows
#define MT_  (L_ / 128)         // 32 m-tiles per batch
#define NTASK_ ((MT_ * (MT_ + 1)) / 2)   // 528 lower-tri tiles per batch

// ---- async global->LDS, 16B per lane (wave-uniform LDS base + lane*16) ----
__device__ __forceinline__ void ld_g2l_16(const bf16_t* g, bf16_t* l) {
  __builtin_amdgcn_global_load_lds(
      (__attribute__((address_space(1))) void*)g,
      (__attribute__((address_space(3))) void*)l, 16, 0, 0);
}

// ---- fused fp32->bf16 convert; W rows permuted so rope pairs (t,t+512)
// become adjacent output columns (2t, 2t+1). Same permutation for Wq,Wk
// leaves q.k dot products invariant. ----
__global__ void cvt_all(const float* __restrict__ hs, const float* __restrict__ wq,
                        const float* __restrict__ wk, bf16_t* __restrict__ hs_b,
                        bf16_t* __restrict__ wq_b, bf16_t* __restrict__ wk_b) {
  const int N_HS = M_ * DIM_ / 4, N_W = DIM_ * DIM_ / 4;
  int i = blockIdx.x * blockDim.x + threadIdx.x;
  const float* s; bf16_t* d; int idx, dst;
  if (i < N_HS) { s = hs; d = hs_b; idx = i; dst = i; }
  else {
    int iw = i - N_HS;
    if (iw < N_W) { s = wq; d = wq_b; } else { s = wk; d = wk_b; iw -= N_W; }
    idx = iw;
    int r = iw >> 8, c4 = iw & 255;                 // 256 float4 per row
    int pr = (r < 512) ? 2 * r : 2 * (r - 512) + 1; // pairing permutation
    dst = pr * 256 + c4;
  }
  float4 v = ((const float4*)s)[idx];
  bf16x4 o = { (bf16_t)v.x, (bf16_t)v.y, (bf16_t)v.z, (bf16_t)v.w };
  ((bf16x4*)d)[dst] = o;
}

// ---- pipelined 128x128 bt-GEMM K-loop, K=1024, BK=32 ----
// wave grid 2x2: wave owns 64m x 64n. A-frags loaded DIRECT from global
// right after the barrier (L2-resident; vmcnt hidden behind B ds_reads).
// B staged in LDS, double-buffered 2x8KB, XOR-swizzled (0 conflicts, R3).
// ONE __syncthreads per kk: its vmcnt drain waits on the B-prefetch issued
// a full compute phase earlier (true 1-deep pipeline).
// Register budget (no launch_bounds min-occupancy -> NO forced spill, R4 bug):
// acc 64 + af 32 + bfr 32 + addr ~20 = ~150 VGPR -> ~3 waves/SIMD naturally.
__device__ __forceinline__ void k_loop(const bf16_t* __restrict__ A,
                                       const bf16_t* __restrict__ B,
                                       bf16_t* Bs, f32x4 (&acc)[4][4]) {
  const int tid = threadIdx.x, wave = tid >> 6, lane = tid & 63;
  const int quad = lane >> 4, l16 = lane & 15;
  const int srow = lane >> 2;                              // 0..15 in segment
  const int scol = ((lane & 3) ^ ((lane >> 3) & 3)) * 8;   // swizzled chunk
  const int rsw  = ((l16 >> 1) & 3) * 8;                   // read-side swizzle
  const int wm = (wave >> 1) * 64, wnseg = (wave & 1) * 4;

  auto stage = [&](int buf, int kk) {
#pragma unroll
    for (int c = 0; c < 2; ++c) {
      int seg = c * 4 + wave;                    // 8 segs of 16 rows x 32 cols
      int row = seg * 16 + srow;
      ld_g2l_16(B + (size_t)row * DIM_ + kk + scol, Bs + buf * 4096 + seg * 512);
    }
  };

  stage(0, 0);
  for (int kk = 0; kk < DIM_; kk += 32) {
    int buf = (kk >> 5) & 1;
    int kkn = (kk + 32 < DIM_) ? kk + 32 : 0;    // last-iter clamp (harmless refetch)
    __syncthreads();                             // drains prefetch; WAR-protects buf^1
    stage(buf ^ 1, kkn);                         // prefetch next B tile
    bf16x8 af[4], bfr[4];
#pragma unroll
    for (int i = 0; i < 4; ++i)
      af[i] = *(const bf16x8*)(A + (size_t)(wm + i * 16 + l16) * DIM_ + kk + quad * 8);
#pragma unroll
    for (int j = 0; j < 4; ++j)
      bfr[j] = *(const bf16x8*)(Bs + buf * 4096 + (wnseg + j) * 512 + l16 * 32 +
                                ((quad * 8) ^ rsw));
#pragma unroll
    for (int i = 0; i < 4; ++i)
#pragma unroll
      for (int j = 0; j < 4; ++j)
        acc[i][j] = __builtin_amdgcn_mfma_f32_16x16x32_bf16(af[i], bfr[j],
                                                            acc[i][j], 0, 0, 0);
  }
}

// ---- projection GEMM + fused RoPE epilogue: C = rope(A @ W'^T) ----
// Permuted cols: even c -> orig t=c>>1 (first half), odd c -> orig t+512.
// Partner element is the adjacent lane (shfl_xor 1).
__global__ __launch_bounds__(256)
void proj_gemm(const bf16_t* __restrict__ A, const bf16_t* __restrict__ Wqb,
               const bf16_t* __restrict__ Wkb, bf16_t* __restrict__ Cq,
               bf16_t* __restrict__ Ck) {
  const bf16_t* Bm = (blockIdx.z == 0) ? Wqb : Wkb;
  bf16_t* Cm = (blockIdx.z == 0) ? Cq : Ck;
  __shared__ __attribute__((aligned(16))) bf16_t Bs[2 * 4096];
  const int tid = threadIdx.x;
  const int wave = tid >> 6, lane = tid & 63;
  const int quad = lane >> 4, l16 = lane & 15;
  const int wm = (wave >> 1) * 64, wn = (wave & 1) * 64;
  const int m0 = blockIdx.y * 128, n0 = blockIdx.x * 128;

  f32x4 acc[4][4] = {};
  k_loop(A + (size_t)m0 * DIM_, Bm + (size_t)n0 * DIM_, Bs, acc);

#pragma unroll
  for (int i = 0; i < 4; ++i)
#pragma unroll
    for (int j = 0; j < 4; ++j)
#pragma unroll
      for (int r = 0; r < 4; ++r) {
        int m = m0 + wm + i * 16 + quad * 4 + r;   // C/D: row=quad*4+reg
        int c = n0 + wn + j * 16 + l16;            //      col=lane&15
        float val = (float)(bf16_t)acc[i][j][r];   // ref: q cast to bf16 pre-rope
        float par = __shfl_xor(val, 1);
        int t = c >> 1;
        int pos = m & (L_ - 1);
        float ang = (float)pos * exp2f((float)t * (-5.0f / 512.0f));
        float cb = (float)(bf16_t)cosf(ang), sb = (float)(bf16_t)sinf(ang);
        float ov = (c & 1) ? (val * cb + par * sb) : (val * cb - par * sb);
        Cm[(size_t)m * DIM_ + c] = (bf16_t)ov;
      }
}

// ---- causal exp-rowsum: o[b,m] = sum_{n<=m} exp(q_m . k_n / 32) ----
__global__ __launch_bounds__(256)
void attn_rowsum(const bf16_t* __restrict__ Q, const bf16_t* __restrict__ Kc,
                 float* __restrict__ o) {
  int t = blockIdx.x;
  int b = t / NTASK_;
  t -= b * NTASK_;
  int mi = (int)((sqrtf(8.0f * (float)t + 1.0f) - 1.0f) * 0.5f);
  while ((mi + 1) * (mi + 2) / 2 <= t) ++mi;
  while (mi * (mi + 1) / 2 > t) --mi;
  int nt = t - mi * (mi + 1) / 2;

  __shared__ __attribute__((aligned(16))) bf16_t Bs[2 * 4096];
  const int tid = threadIdx.x;
  const int wave = tid >> 6, lane = tid & 63;
  const int quad = lane >> 4, l16 = lane & 15;
  const int wm = (wave >> 1) * 64, wn = (wave & 1) * 64;

  const bf16_t* A  = Q  + (size_t)b * L_ * DIM_ + (size_t)mi * 128 * DIM_;
  const bf16_t* Bp = Kc + (size_t)b * L_ * DIM_ + (size_t)nt * 128 * DIM_;

  f32x4 acc[4][4] = {};
  k_loop(A, Bp, Bs, acc);

  const bool masked = (nt == mi);   // tile touches the diagonal
#pragma unroll
  for (int i = 0; i < 4; ++i) {
#pragma unroll
    for (int r = 0; r < 4; ++r) {
      int grow = mi * 128 + wm + i * 16 + quad * 4 + r;   // row in batch
      float sum = 0.0f;
#pragma unroll
      for (int j = 0; j < 4; ++j) {
        int gcol = nt * 128 + wn + j * 16 + l16;
        float e = __expf(acc[i][j][r] * 0.03125f);        // /sqrt(1024)
        if (!masked || gcol <= grow) sum += e;
      }
      sum += __shfl_xor(sum, 1);
      sum += __shfl_xor(sum, 2);
      sum += __shfl_xor(sum, 4);
      sum += __shfl_xor(sum, 8);
      if (l16 == 0)
        atomicAdd(&o[b * L_ + grow], sum);
    }
  }
}

// ---- tiny MLP epilogue ----
__global__ __launch_bounds__(256)
void mlp_out_kernel(const float* __restrict__ o, const float* __restrict__ fc1_w,
                    const float* __restrict__ fc1_b, const float* __restrict__ fc2_w,
                    const float* __restrict__ fc2_b, float* __restrict__ out) {
  const int R = 16;
  int row0 = blockIdx.x * R;
  int tid = threadIdx.x;
  __shared__ float h[R][16];
  {
    int rl = tid >> 4, i = tid & 15;
    float s = o[row0 + rl];
    h[rl][i] = fmaxf(fc1_w[i] * s + fc1_b[i], 0.0f);
  }
  __syncthreads();
  int d = tid * 4;
  float w[4][16];
#pragma unroll
  for (int c = 0; c < 4; ++c)
#pragma unroll
    for (int i = 0; i < 16; ++i) w[c][i] = fc2_w[(d + c) * 16 + i];
  float4 bb = *(const float4*)(fc2_b + d);
  for (int rl = 0; rl < R; ++rl) {
    float4 v = bb;
#pragma unroll
    for (int i = 0; i < 16; ++i) {
      float hv = h[rl][i];
      v.x += w[0][i] * hv; v.y += w[1][i] * hv;
      v.z += w[2][i] * hv; v.w += w[3][i] * hv;
    }
    *(float4*)(out + (size_t)(row0 + rl) * DIM_ + d) = v;
  }
}

extern "C" void kernel_launch(void* const* d_in, const int* in_sizes, int n_in,
                              void* d_out, int out_size, void* d_ws, size_t ws_size,
                              hipStream_t stream) {
  const float* hs    = (const float*)d_in[0];
  const float* Wq    = (const float*)d_in[1];
  const float* Wk    = (const float*)d_in[2];
  const float* fc1_w = (const float*)d_in[3];
  const float* fc1_b = (const float*)d_in[4];
  const float* fc2_w = (const float*)d_in[5];
  const float* fc2_b = (const float*)d_in[6];
  float* out = (float*)d_out;

  char* ws = (char*)d_ws;
  bf16_t* hs_bf = (bf16_t*)ws; ws += (size_t)M_ * DIM_ * 2;
  bf16_t* wq_bf = (bf16_t*)ws; ws += (size_t)DIM_ * DIM_ * 2;
  bf16_t* wk_bf = (bf16_t*)ws; ws += (size_t)DIM_ * DIM_ * 2;
  bf16_t* q_bf  = (bf16_t*)ws; ws += (size_t)M_ * DIM_ * 2;
  bf16_t* k_bf  = (bf16_t*)ws; ws += (size_t)M_ * DIM_ * 2;
  float*  o     = (float*)ws;  // M_ floats

  const int n4 = (M_ * DIM_ + 2 * DIM_ * DIM_) / 4;
  cvt_all<<<n4 / 256, 256, 0, stream>>>(hs, Wq, Wk, hs_bf, wq_bf, wk_bf);

  hipMemsetAsync(o, 0, M_ * sizeof(float), stream);

  dim3 gg(DIM_ / 128, M_ / 128, 2);
  proj_gemm<<<gg, 256, 0, stream>>>(hs_bf, wq_bf, wk_bf, q_bf, k_bf);

  attn_rowsum<<<B_ * NTASK_, 256, 0, stream>>>(q_bf, k_bf, o);

  mlp_out_kernel<<<M_ / 16, 256, 0, stream>>>(o, fc1_w, fc1_b, fc2_w, fc2_b, out);
}